// Round 9
// baseline (208.970 us; speedup 1.0000x reference)
//
#include <hip/hip_runtime.h>

// ---------------------------------------------------------------------------
// BaseWindowAttention on MI355X (gfx950) — fused 3-kernel pipeline
// x:[2,256,256,256]f32, w_qkv:[256,768]f32, pos_emb:[15,15]f32,
// w_out:[256,256]f32, b_out:[256]f32, rel_idx:[64,64,2]i32
// out:[2,256,256,256]f32
//
//  prep:     w_qkv^T, w_out^T -> bf16 (ws), biasP[lane][64] f32 (ws)
//  qkvproj:  v4 — R4 geometry + 2-phase static-dbuf pipeline.
//            Block = 128 rows (grid 1024), 4 waves (2x2 of 64x64), BK=32.
//            A (x-tile) converted once into a 64KB chunk-XOR'd LDS tile.
//            B staged via global_load_lds into TWO statically-named 8KB
//            buffers; stage(t+1) issued BEFORE compute(t), one barrier per
//            K-step. (R5 lesson: runtime dbuf index kills alias analysis ->
//            vmcnt(0) drains before every ds_read. Static names fix it.
//            R7 lesson: fragment-direct global loads scatter 16 cache lines
//            per instruction -> never bypass coalesced gload_lds staging.)
//  attn_out: fused window attention + output projection. Block = 1 window,
//            8 waves (1 head each). P aliased onto the V^T buffer -> 64KB
//            LDS -> 2 blocks/CU. (unchanged)
// ---------------------------------------------------------------------------

typedef __bf16 bf16_t;
typedef __bf16 bf16x8 __attribute__((ext_vector_type(8)));
typedef __bf16 bf16x4 __attribute__((ext_vector_type(4)));
typedef float  f32x4  __attribute__((ext_vector_type(4)));

#define MFMA_BF16(a, b, c) __builtin_amdgcn_mfma_f32_16x16x32_bf16((a), (b), (c), 0, 0, 0)
#define SM_SCALE 0.17677669529663687f  // 32^-0.5

// ws layout (bytes)
#define WQKVT_OFF 0u          // bf16 [768][256]
#define WOUTT_OFF 393216u     // bf16 [256][256]
#define BIASP_OFF 524288u     // f32  [64 lanes][64]  (pre-permuted)
#define QKV_OFF   540672u     // bf16 [131072][768]

__device__ __forceinline__ void gload16(const void* g, void* l) {
    __builtin_amdgcn_global_load_lds(
        (const __attribute__((address_space(1))) unsigned int*)g,
        (__attribute__((address_space(3))) unsigned int*)l,
        16, 0, 0);
}

// ---------------------------------------------------------------------------
__global__ __launch_bounds__(256) void prep_kernel(
    const float* __restrict__ w_qkv, const float* __restrict__ w_out,
    const float* __restrict__ pos_emb, const int* __restrict__ rel_idx,
    bf16_t* __restrict__ wqkvT, bf16_t* __restrict__ woutT,
    float* __restrict__ biasP)
{
    int idx = blockIdx.x * 256 + threadIdx.x;
    if (idx < 196608) {                 // wqkvT[n][k] = w_qkv[k][n]
        int n = idx >> 8, k = idx & 255;
        wqkvT[idx] = (bf16_t)w_qkv[k * 768 + n];
    } else if (idx < 262144) {          // woutT[n][k] = w_out[k][n]
        int t = idx - 196608;
        int n = t >> 8, k = t & 255;
        woutT[t] = (bf16_t)w_out[k * 256 + n];
    } else if (idx < 266240) {          // biasP[lane][e]: per-lane MFMA layout
        int t = idx - 262144;
        int lane = t >> 6, e = t & 63;
        int ni = e >> 4, mi = (e >> 2) & 3, rg = e & 3;
        int i = 16 * ni + (lane & 15);          // query index
        int j = 16 * mi + 4 * (lane >> 4) + rg; // key index
        int i0 = rel_idx[(i * 64 + j) * 2 + 0];
        int i1 = rel_idx[(i * 64 + j) * 2 + 1];
        biasP[t] = pos_emb[i0 * 15 + i1];
    }
}

// ---------------------------------------------------------------------------
// Fused x-convert + qkv GEMM v4 (pipelined).
// C[M=131072][N=768] = bf16(x)[M][256] @ wT^T, C bf16.
__global__ __launch_bounds__(256, 2) void qkvproj_kernel(
    const float* __restrict__ x, const bf16_t* __restrict__ wT,
    bf16_t* __restrict__ qkv)
{
    __shared__ __align__(16) bf16_t A_s[128 * 256];   // 64KB, block-resident
    __shared__ __align__(16) bf16_t B0_s[128 * 32];   // 8KB  (static dbuf)
    __shared__ __align__(16) bf16_t B1_s[128 * 32];   // 8KB

    const int tid = threadIdx.x;
    const int lane = tid & 63, wv = tid >> 6;
    const int g = lane >> 4, c = lane & 15;
    const int wm = wv >> 1, wn = wv & 1;
    const int m0 = blockIdx.x << 7;
    f32x4 z4 = {0.f, 0.f, 0.f, 0.f};

    f32x4 acc[4][4];

    // stage one B tile (512 x 16B chunks, 2/thread), coalesced gload_lds
    auto stage = [&](bf16_t* dst, int n0, int ks) {
#pragma unroll
        for (int i = 0; i < 2; ++i) {
            int q = i * 256 + tid;
            int row = q >> 2;
            int pl = (q & 3) ^ (row & 3);
            gload16(wT + (n0 + row) * 256 + ks * 32 + pl * 8,
                    (char*)dst + (i * 256 + wv * 64) * 16);
        }
    };

    // ds_read A+B fragments, 16 MFMA into acc
    auto compute = [&](const bf16_t* Bb, int ks) {
        const f32x4* Bsf = (const f32x4*)Bb;
        bf16x8 af[4], bfr[4];
#pragma unroll
        for (int mi = 0; mi < 4; ++mi) {
            int r = wm * 64 + mi * 16 + c;
            af[mi] = *(const bf16x8*)(A_s + r * 256 + (((4 * ks + g) ^ (r & 31)) << 3));
        }
#pragma unroll
        for (int ni = 0; ni < 4; ++ni) {
            int r2 = wn * 64 + ni * 16 + c;
            f32x4 tt = Bsf[r2 * 4 + (g ^ (r2 & 3))];
            bfr[ni] = __builtin_bit_cast(bf16x8, tt);
        }
#pragma unroll
        for (int mi = 0; mi < 4; ++mi)
#pragma unroll
            for (int ni = 0; ni < 4; ++ni)
                acc[mi][ni] = MFMA_BF16(af[mi], bfr[ni], acc[mi][ni]);
    };

    // issue first B stage; its flight overlaps the whole A-conversion phase
    stage(B0_s, 0, 0);

    // A: x (f32) -> bf16 into A_s; 4096 16B chunks, XOR slot = ci ^ (row&31)
#pragma unroll
    for (int jj = 0; jj < 16; ++jj) {
        int q = jj * 512 + tid * 2;          // f32x4-chunk index (8192 total)
        int row = q >> 6;
        int ci = (q & 63) >> 1;              // 16B bf16-chunk 0..31
        const f32x4* xp = (const f32x4*)(x + (size_t)(m0 + row) * 256 + (q & 63) * 4);
        f32x4 a = xp[0], b = xp[1];
        bf16x8 t;
        t[0] = (bf16_t)a[0]; t[1] = (bf16_t)a[1];
        t[2] = (bf16_t)a[2]; t[3] = (bf16_t)a[3];
        t[4] = (bf16_t)b[0]; t[5] = (bf16_t)b[1];
        t[6] = (bf16_t)b[2]; t[7] = (bf16_t)b[3];
        *(bf16x8*)(A_s + row * 256 + ((ci ^ (row & 31)) << 3)) = t;
    }
    __syncthreads();   // drains A lgkm + B0 vmcnt

    for (int bn = 0; bn < 6; ++bn) {
        const int n0 = bn << 7;
#pragma unroll
        for (int i = 0; i < 4; ++i)
#pragma unroll
            for (int j = 0; j < 4; ++j) acc[i][j] = z4;

#pragma unroll
        for (int kp = 0; kp < 4; ++kp) {
            // even half: stage B1(ks+1) ahead, compute B0(ks)
            stage(B1_s, n0, 2 * kp + 1);
            compute(B0_s, 2 * kp);
            __syncthreads();
            // odd half: stage B0(next tile) ahead, compute B1(ks+1)
            if (kp < 3)      stage(B0_s, n0, 2 * kp + 2);
            else if (bn < 5) stage(B0_s, n0 + 128, 0);
            compute(B1_s, 2 * kp + 1);
            __syncthreads();
        }

        // epilogue for this column tile (global stores, no LDS dependence)
#pragma unroll
        for (int mi = 0; mi < 4; ++mi)
#pragma unroll
            for (int ni = 0; ni < 4; ++ni)
#pragma unroll
                for (int rg = 0; rg < 4; ++rg) {
                    int grow = m0 + wm * 64 + mi * 16 + 4 * g + rg;
                    int gcol = n0 + wn * 64 + ni * 16 + c;
                    qkv[(size_t)grow * 768 + gcol] = (bf16_t)acc[mi][ni][rg];
                }
    }
}

// ---------------------------------------------------------------------------
// Fused window attention + output projection. Grid 2048 (one per window),
// 512 threads = 8 waves = 8 heads. Swapped QK^T, in-register softmax,
// O^T = V^T P^T. P tile ALIASED onto the V^T buffer (V frags hoisted to
// registers first; per-wave DS ops are in-order). 64KB LDS -> 2 blocks/CU.
__global__ __launch_bounds__(512, 2) void attn_out_kernel(
    const bf16_t* __restrict__ qkv, const float* __restrict__ biasP,
    const bf16_t* __restrict__ woutT, const float* __restrict__ b_out,
    float* __restrict__ out)
{
    __shared__ __align__(16) bf16_t PV_s[8][2048];   // 4KB/wave: Vt, then P
    __shared__ __align__(16) bf16_t AO_s[64 * 256];  // 32KB

    const int tid = threadIdx.x;
    const int lane = tid & 63, wv = tid >> 6;
    const int g = lane >> 4, c = lane & 15;
    const int b = blockIdx.x;
    const int h = wv;
    const int rbase = (b >> 10) * 65536 + ((b >> 5) & 31) * 2048 + (b & 31) * 8;

    bf16_t* Vw = PV_s[wv];
    bf16_t* Pw = PV_s[wv];   // alias (temporally disjoint per wave)
    const float* bp = biasP + lane * 64;
    f32x4 z4 = {0.f, 0.f, 0.f, 0.f};

    // K (A-frag) / Q (B-frag): 16B per lane straight from global.
    bf16x8 qf[4], kf[4];
#pragma unroll
    for (int mi = 0; mi < 4; ++mi) {
        int t = mi * 16 + c;
        size_t r = (size_t)(rbase + (t >> 3) * 256 + (t & 7));
        const bf16_t* rowp = qkv + r * 768 + h * 32;
        qf[mi] = *(const bf16x8*)(rowp + g * 8);
        kf[mi] = *(const bf16x8*)(rowp + 256 + g * 8);
    }
    // V -> Vt LDS (transposed, swizzled): Vt[dh][tok]
    {
        int t = lane;
        size_t r = (size_t)(rbase + (t >> 3) * 256 + (t & 7));
        const bf16_t* rowp = qkv + r * 768 + 512 + h * 32;
#pragma unroll
        for (int d0 = 0; d0 < 4; ++d0) {
            bf16x8 v = *(const bf16x8*)(rowp + d0 * 8);
#pragma unroll
            for (int j = 0; j < 8; ++j) {
                int dh = d0 * 8 + j;
                Vw[dh * 64 + ((((t >> 3) ^ (dh & 7)) << 3) | (t & 7))] = v[j];
            }
        }
    }
    // hoist V^T A-fragments to registers (Vw dead afterwards -> P reuses it)
    bf16x8 vbA[2][2];
#pragma unroll
    for (int ks = 0; ks < 2; ++ks)
#pragma unroll
        for (int mi = 0; mi < 2; ++mi) {
            int dh = mi * 16 + c;
            vbA[ks][mi] = *(const bf16x8*)(Vw + dh * 64 + (((4 * ks + g) ^ (dh & 7)) << 3));
        }

    // per-ni: QK^T -> softmax -> P tile -> O^T = V^T P^T -> ao LDS
#pragma unroll
    for (int ni = 0; ni < 4; ++ni) {
        f32x4 s[4];
        __builtin_amdgcn_s_setprio(1);
#pragma unroll
        for (int mi = 0; mi < 4; ++mi)
            s[mi] = MFMA_BF16(kf[mi], qf[ni], z4);
        __builtin_amdgcn_s_setprio(0);

        float mx = -1e30f;
#pragma unroll
        for (int mi = 0; mi < 4; ++mi) {
            f32x4 bb = *(const f32x4*)(bp + ni * 16 + mi * 4);
#pragma unroll
            for (int rg = 0; rg < 4; ++rg) {
                float t = fmaf(s[mi][rg], SM_SCALE, bb[rg]);
                s[mi][rg] = t;
                mx = fmaxf(mx, t);
            }
        }
        mx = fmaxf(mx, __shfl_xor(mx, 16));
        mx = fmaxf(mx, __shfl_xor(mx, 32));
        float sm = 0.f;
#pragma unroll
        for (int mi = 0; mi < 4; ++mi)
#pragma unroll
            for (int rg = 0; rg < 4; ++rg) {
                float p = __expf(s[mi][rg] - mx);
                s[mi][rg] = p;
                sm += p;
            }
        sm += __shfl_xor(sm, 16);
        sm += __shfl_xor(sm, 32);
        float inv = 1.0f / sm;

        bf16_t* Pl = Pw + (ni & 1) * 1024;
#pragma unroll
        for (int mi = 0; mi < 4; ++mi) {
            bf16x4 pk;
#pragma unroll
            for (int rg = 0; rg < 4; ++rg) pk[rg] = (bf16_t)s[mi][rg];
            *(bf16x4*)(Pl + c * 64 + (((2 * mi + (g >> 1)) ^ (c & 7)) << 3) + 4 * (g & 1)) = pk;
        }

        // O^T = V^T P^T : lane(c,g) -> O^T[dh=16mi+4g+rg][tok=16ni+c]
        f32x4 o0 = z4, o1 = z4;
        __builtin_amdgcn_s_setprio(1);
#pragma unroll
        for (int ks = 0; ks < 2; ++ks) {
            bf16x8 pa = *(const bf16x8*)(Pl + c * 64 + (((4 * ks + g) ^ (c & 7)) << 3));
            o0 = MFMA_BF16(vbA[ks][0], pa, o0);
            o1 = MFMA_BF16(vbA[ks][1], pa, o1);
        }
        __builtin_amdgcn_s_setprio(0);
        // normalize (inv is per q-row, uniform over g) + ao write (b64)
        int tok = 16 * ni + c;
#pragma unroll
        for (int mi = 0; mi < 2; ++mi) {
            f32x4 ov = (mi == 0) ? o0 : o1;
            bf16x4 pk;
#pragma unroll
            for (int rg = 0; rg < 4; ++rg) pk[rg] = (bf16_t)(ov[rg] * inv);
            int ci = h * 4 + mi * 2 + (g >> 1);
            *(bf16x4*)((char*)AO_s + tok * 512 + ((ci ^ (tok & 31)) << 4) + (g & 1) * 8) = pk;
        }
    }
    __syncthreads();

    // GEMM2: out[64 tok][256] = ao @ woutT^T + b_out. Wave wv owns 32 cols.
    f32x4 acc2[4][2];
#pragma unroll
    for (int i = 0; i < 4; ++i) { acc2[i][0] = z4; acc2[i][1] = z4; }

    for (int ks = 0; ks < 8; ++ks) {
        bf16x8 af2[4], bf2[2];
#pragma unroll
        for (int mi = 0; mi < 4; ++mi) {
            int rr = 16 * mi + c;
            af2[mi] = *(const bf16x8*)((char*)AO_s + rr * 512 + (((4 * ks + g) ^ (rr & 31)) << 4));
        }
#pragma unroll
        for (int nj = 0; nj < 2; ++nj)
            bf2[nj] = *(const bf16x8*)(woutT + (size_t)(32 * wv + 16 * nj + c) * 256 + 32 * ks + 8 * g);
#pragma unroll
        for (int mi = 0; mi < 4; ++mi)
#pragma unroll
            for (int nj = 0; nj < 2; ++nj)
                acc2[mi][nj] = MFMA_BF16(af2[mi], bf2[nj], acc2[mi][nj]);
    }

#pragma unroll
    for (int nj = 0; nj < 2; ++nj) {
        int gcol = 32 * wv + 16 * nj + c;
        float bo = b_out[gcol];
#pragma unroll
        for (int mi = 0; mi < 4; ++mi)
#pragma unroll
            for (int rg = 0; rg < 4; ++rg) {
                int tok = 16 * mi + 4 * g + rg;
                size_t r = (size_t)(rbase + (tok >> 3) * 256 + (tok & 7));
                out[r * 256 + gcol] = acc2[mi][nj][rg] + bo;
            }
    }
}

// ---------------------------------------------------------------------------
extern "C" void kernel_launch(void* const* d_in, const int* in_sizes, int n_in,
                              void* d_out, int out_size, void* d_ws, size_t ws_size,
                              hipStream_t stream) {
    const float* x       = (const float*)d_in[0];
    const float* w_qkv   = (const float*)d_in[1];
    const float* pos_emb = (const float*)d_in[2];
    const float* w_out   = (const float*)d_in[3];
    const float* b_out   = (const float*)d_in[4];
    const int*   rel_idx = (const int*)d_in[5];

    char* ws = (char*)d_ws;
    bf16_t* wqkvT = (bf16_t*)(ws + WQKVT_OFF);
    bf16_t* woutT = (bf16_t*)(ws + WOUTT_OFF);
    float*  biasP = (float*)(ws + BIASP_OFF);
    bf16_t* qkv   = (bf16_t*)(ws + QKV_OFF);   // ~192.5MB of ws
    float*  out   = (float*)d_out;

    prep_kernel<<<1040, 256, 0, stream>>>(w_qkv, w_out, pos_emb, rel_idx,
                                          wqkvT, woutT, biasP);
    qkvproj_kernel<<<1024, 256, 0, stream>>>(x, wqkvT, qkv);
    attn_out_kernel<<<2048, 512, 0, stream>>>(qkv, biasP, woutT, b_out, out);
}

// Round 10
// 154.141 us; speedup vs baseline: 1.3557x; 1.3557x over previous
//
#include <hip/hip_runtime.h>

// ---------------------------------------------------------------------------
// BaseWindowAttention on MI355X (gfx950) — FULLY FUSED single-pass pipeline
// x:[2,256,256,256]f32, w_qkv:[256,768]f32, pos_emb:[15,15]f32,
// w_out:[256,256]f32, b_out:[256]f32, rel_idx:[64,64,2]i32
// out:[2,256,256,256]f32
//
//  prep:  wpk (w_qkv repacked in MFMA-fragment order, per (head,strip,ni,ks):
//         1KB coalesced wave-loads), w_out^T bf16, biasP[lane][64] f32.
//  fused: block = 1 window (2048 blocks, 512 thr = 8 waves = 8 heads).
//         Phase1: x window -> bf16 LDS tile Xs (32KB, chunk-XOR).
//         Phase2: per wave, qkv GEMM for its own head (B-frags coalesced
//                 from wpk/L2, A-frags from Xs); each strip's C goes through
//                 a 5KB per-wave scratch (Q/K:[64][40] pad, V:[32][72]
//                 transposed) -> frags hoisted to regs.
//         Phase3: attention (swapped QK^T, in-reg softmax, O^T=V^T P^T),
//                 P-tile reuses the per-wave scratch. (verbatim from R9)
//         Phase4: GEMM2 out = ao @ w_out + b, AO tile unioned onto Xs.
//         No qkv intermediate: HBM traffic 670MB -> 268MB.
//  R5/R7/R9 lessons embedded: static buffer names, coalesced frag loads via
//  pre-packing, per-wave in-order DS alias reuse, 72KB LDS -> 2 blocks/CU.
// ---------------------------------------------------------------------------

typedef __bf16 bf16_t;
typedef __bf16 bf16x8 __attribute__((ext_vector_type(8)));
typedef __bf16 bf16x4 __attribute__((ext_vector_type(4)));
typedef float  f32x4  __attribute__((ext_vector_type(4)));

#define MFMA_BF16(a, b, c) __builtin_amdgcn_mfma_f32_16x16x32_bf16((a), (b), (c), 0, 0, 0)
#define SM_SCALE 0.17677669529663687f  // 32^-0.5

// ws layout (bytes)
#define WPK_OFF   0u          // bf16 [8h][3s][2ni][8ks][64 lane][8] = 384KB
#define WOUTT_OFF 393216u     // bf16 [256][256]
#define BIASP_OFF 524288u     // f32  [64 lanes][64]  (pre-permuted)

// ---------------------------------------------------------------------------
__global__ __launch_bounds__(256) void prep_kernel(
    const float* __restrict__ w_qkv, const float* __restrict__ w_out,
    const float* __restrict__ pos_emb, const int* __restrict__ rel_idx,
    bf16_t* __restrict__ wpk, bf16_t* __restrict__ woutT,
    float* __restrict__ biasP)
{
    int idx = blockIdx.x * 256 + threadIdx.x;
    if (idx < 196608) {
        // wpk fragment order: tile t = ((h*3+s)*2+ni)*8+ks, entry (lane,j)
        // value = w_qkv[k][n], n = s*256+h*32+ni*16+c, k = ks*32+g*8+j
        int j = idx & 7, lane = (idx >> 3) & 63, t = idx >> 9;
        int ks = t & 7, ni = (t >> 3) & 1, hs = t >> 4;
        int s = hs % 3, h = hs / 3;
        int c = lane & 15, g = lane >> 4;
        int n = s * 256 + h * 32 + ni * 16 + c;
        int k = ks * 32 + g * 8 + j;
        wpk[idx] = (bf16_t)w_qkv[k * 768 + n];
    } else if (idx < 262144) {          // woutT[n][k] = w_out[k][n]
        int t = idx - 196608;
        int n = t >> 8, k = t & 255;
        woutT[t] = (bf16_t)w_out[k * 256 + n];
    } else if (idx < 266240) {          // biasP[lane][e]: per-lane MFMA layout
        int t = idx - 262144;
        int lane = t >> 6, e = t & 63;
        int ni = e >> 4, mi = (e >> 2) & 3, rg = e & 3;
        int i = 16 * ni + (lane & 15);          // query index
        int j = 16 * mi + 4 * (lane >> 4) + rg; // key index
        int i0 = rel_idx[(i * 64 + j) * 2 + 0];
        int i1 = rel_idx[(i * 64 + j) * 2 + 1];
        biasP[t] = pos_emb[i0 * 15 + i1];
    }
}

// ---------------------------------------------------------------------------
// Fully fused window kernel. Grid 2048 (one per window), 512 thr = 8 waves.
__global__ __launch_bounds__(512, 2) void fused_kernel(
    const float* __restrict__ x, const bf16_t* __restrict__ wpk,
    const float* __restrict__ biasP, const bf16_t* __restrict__ woutT,
    const float* __restrict__ b_out, float* __restrict__ out)
{
    // XA_s: x-tile (phase 1-2), then AO tile (phase 3-4). 32KB.
    __shared__ __align__(16) bf16_t XA_s[64 * 256];
    // per-wave scratch: Q/K [64][40], V [32][72], then P tile [2][1024]. 40KB.
    __shared__ __align__(16) bf16_t SB_s[8][2560];

    const int tid = threadIdx.x;
    const int lane = tid & 63, wv = tid >> 6;
    const int g = lane >> 4, c = lane & 15;
    const int b = blockIdx.x;
    const int h = wv;
    const int rbase = (b >> 10) * 65536 + ((b >> 5) & 31) * 2048 + (b & 31) * 8;

    bf16_t* SB = SB_s[wv];
    const float* bp = biasP + lane * 64;
    f32x4 z4 = {0.f, 0.f, 0.f, 0.f};

    // ---- early-issue B-frags for strip 0 (q): independent of Xs staging
    const bf16_t* wb0 = wpk + (size_t)((h * 3 + 0) * 2) * 8 * 512;
    bf16x8 bfr[2][8];
#pragma unroll
    for (int ni = 0; ni < 2; ++ni)
#pragma unroll
        for (int ks = 0; ks < 8; ++ks)
            bfr[ni][ks] = *(const bf16x8*)(wb0 + (ni * 8 + ks) * 512 + lane * 8);

    // ---- phase 1: x window -> Xs bf16 (2048 x 16B chunks, 4/thread)
#pragma unroll
    for (int jj = 0; jj < 4; ++jj) {
        int q = jj * 512 + tid;          // chunk index 0..2047
        int tok = q >> 5, ci = q & 31;   // 32 chunks per 64-token row
        int r = rbase + (tok >> 3) * 256 + (tok & 7);
        const f32x4* xp = (const f32x4*)(x + (size_t)r * 256 + ci * 8);
        f32x4 a = xp[0], bq = xp[1];
        bf16x8 t;
        t[0] = (bf16_t)a[0];  t[1] = (bf16_t)a[1];
        t[2] = (bf16_t)a[2];  t[3] = (bf16_t)a[3];
        t[4] = (bf16_t)bq[0]; t[5] = (bf16_t)bq[1];
        t[6] = (bf16_t)bq[2]; t[7] = (bf16_t)bq[3];
        *(bf16x8*)(XA_s + tok * 256 + ((ci ^ (tok & 31)) << 3)) = t;
    }
    __syncthreads();

    // ---- phase 2: per-head qkv GEMM, strip by strip
    bf16x8 qf[4], kf[4], vbA[2][2];

#pragma unroll
    for (int s = 0; s < 3; ++s) {
        if (s > 0) {   // strips 1,2: load B-frags now
            const bf16_t* wb = wpk + (size_t)((h * 3 + s) * 2) * 8 * 512;
#pragma unroll
            for (int ni = 0; ni < 2; ++ni)
#pragma unroll
                for (int ks = 0; ks < 8; ++ks)
                    bfr[ni][ks] = *(const bf16x8*)(wb + (ni * 8 + ks) * 512 + lane * 8);
        }
        f32x4 acc[4][2];
#pragma unroll
        for (int i = 0; i < 4; ++i) { acc[i][0] = z4; acc[i][1] = z4; }

#pragma unroll
        for (int ks = 0; ks < 8; ++ks) {
            bf16x8 af[4];
#pragma unroll
            for (int mi = 0; mi < 4; ++mi) {
                int tok = 16 * mi + c;
                af[mi] = *(const bf16x8*)(XA_s + tok * 256 + (((4 * ks + g) ^ (tok & 31)) << 3));
            }
#pragma unroll
            for (int mi = 0; mi < 4; ++mi)
#pragma unroll
                for (int ni = 0; ni < 2; ++ni)
                    acc[mi][ni] = MFMA_BF16(af[mi], bfr[ni][ks], acc[mi][ni]);
        }

        // C layout: [tok = 16mi+4g+rg][dh = 16ni+c]
        if (s < 2) {
            // Q/K strip scratch: [64 tok][40] (32 used; pad-40 -> 2-way reads)
#pragma unroll
            for (int mi = 0; mi < 4; ++mi)
#pragma unroll
                for (int ni = 0; ni < 2; ++ni)
#pragma unroll
                    for (int rg = 0; rg < 4; ++rg)
                        SB[(16 * mi + 4 * g + rg) * 40 + 16 * ni + c] =
                            (bf16_t)acc[mi][ni][rg];
            if (s == 0) {
#pragma unroll
                for (int ni2 = 0; ni2 < 4; ++ni2)   // Q[tok=16ni2+c][8g..]
                    qf[ni2] = *(const bf16x8*)(SB + (16 * ni2 + c) * 40 + 8 * g);
            } else {
#pragma unroll
                for (int mi2 = 0; mi2 < 4; ++mi2)   // K[tok=16mi2+c][8g..]
                    kf[mi2] = *(const bf16x8*)(SB + (16 * mi2 + c) * 40 + 8 * g);
            }
        } else {
            // V strip scratch, transposed: [32 dh][72 tok]
#pragma unroll
            for (int mi = 0; mi < 4; ++mi)
#pragma unroll
                for (int ni = 0; ni < 2; ++ni)
#pragma unroll
                    for (int rg = 0; rg < 4; ++rg)
                        SB[(16 * ni + c) * 72 + (16 * mi + 4 * g + rg)] =
                            (bf16_t)acc[mi][ni][rg];
#pragma unroll
            for (int ks2 = 0; ks2 < 2; ++ks2)       // V^T[dh=16mi2+c][8(4ks2+g)..]
#pragma unroll
                for (int mi2 = 0; mi2 < 2; ++mi2)
                    vbA[ks2][mi2] = *(const bf16x8*)(SB + (16 * mi2 + c) * 72 + 8 * (4 * ks2 + g));
        }
    }
    __syncthreads();   // all waves done with Xs; XA_s becomes AO tile

    // ---- phase 3: attention per head (verbatim R9; P tile reuses SB)
    bf16_t* Pw = SB;
#pragma unroll
    for (int ni = 0; ni < 4; ++ni) {
        f32x4 s[4];
        __builtin_amdgcn_s_setprio(1);
#pragma unroll
        for (int mi = 0; mi < 4; ++mi)
            s[mi] = MFMA_BF16(kf[mi], qf[ni], z4);
        __builtin_amdgcn_s_setprio(0);

        float mx = -1e30f;
#pragma unroll
        for (int mi = 0; mi < 4; ++mi) {
            f32x4 bb = *(const f32x4*)(bp + ni * 16 + mi * 4);
#pragma unroll
            for (int rg = 0; rg < 4; ++rg) {
                float t = fmaf(s[mi][rg], SM_SCALE, bb[rg]);
                s[mi][rg] = t;
                mx = fmaxf(mx, t);
            }
        }
        mx = fmaxf(mx, __shfl_xor(mx, 16));
        mx = fmaxf(mx, __shfl_xor(mx, 32));
        float sm = 0.f;
#pragma unroll
        for (int mi = 0; mi < 4; ++mi)
#pragma unroll
            for (int rg = 0; rg < 4; ++rg) {
                float p = __expf(s[mi][rg] - mx);
                s[mi][rg] = p;
                sm += p;
            }
        sm += __shfl_xor(sm, 16);
        sm += __shfl_xor(sm, 32);
        float inv = 1.0f / sm;

        bf16_t* Pl = Pw + (ni & 1) * 1024;
#pragma unroll
        for (int mi = 0; mi < 4; ++mi) {
            bf16x4 pk;
#pragma unroll
            for (int rg = 0; rg < 4; ++rg) pk[rg] = (bf16_t)s[mi][rg];
            *(bf16x4*)(Pl + c * 64 + (((2 * mi + (g >> 1)) ^ (c & 7)) << 3) + 4 * (g & 1)) = pk;
        }

        // O^T = V^T P^T : lane(c,g) -> O^T[dh=16mi+4g+rg][tok=16ni+c]
        f32x4 o0 = z4, o1 = z4;
        __builtin_amdgcn_s_setprio(1);
#pragma unroll
        for (int ks = 0; ks < 2; ++ks) {
            bf16x8 pa = *(const bf16x8*)(Pl + c * 64 + (((4 * ks + g) ^ (c & 7)) << 3));
            o0 = MFMA_BF16(vbA[ks][0], pa, o0);
            o1 = MFMA_BF16(vbA[ks][1], pa, o1);
        }
        __builtin_amdgcn_s_setprio(0);
        // normalize (inv is per q-row, uniform over g) + AO write (b64)
        int tok = 16 * ni + c;
#pragma unroll
        for (int mi = 0; mi < 2; ++mi) {
            f32x4 ov = (mi == 0) ? o0 : o1;
            bf16x4 pk;
#pragma unroll
            for (int rg = 0; rg < 4; ++rg) pk[rg] = (bf16_t)(ov[rg] * inv);
            int ci = h * 4 + mi * 2 + (g >> 1);
            *(bf16x4*)((char*)XA_s + tok * 512 + ((ci ^ (tok & 31)) << 4) + (g & 1) * 8) = pk;
        }
    }
    __syncthreads();

    // ---- phase 4: GEMM2 out[64 tok][256] = ao @ woutT^T + b_out (verbatim)
    f32x4 acc2[4][2];
#pragma unroll
    for (int i = 0; i < 4; ++i) { acc2[i][0] = z4; acc2[i][1] = z4; }

    for (int ks = 0; ks < 8; ++ks) {
        bf16x8 af2[4], bf2[2];
#pragma unroll
        for (int mi = 0; mi < 4; ++mi) {
            int rr = 16 * mi + c;
            af2[mi] = *(const bf16x8*)((char*)XA_s + rr * 512 + (((4 * ks + g) ^ (rr & 31)) << 4));
        }
#pragma unroll
        for (int nj = 0; nj < 2; ++nj)
            bf2[nj] = *(const bf16x8*)(woutT + (size_t)(32 * wv + 16 * nj + c) * 256 + 32 * ks + 8 * g);
#pragma unroll
        for (int mi = 0; mi < 4; ++mi)
#pragma unroll
            for (int nj = 0; nj < 2; ++nj)
                acc2[mi][nj] = MFMA_BF16(af2[mi], bf2[nj], acc2[mi][nj]);
    }

#pragma unroll
    for (int nj = 0; nj < 2; ++nj) {
        int gcol = 32 * wv + 16 * nj + c;
        float bo = b_out[gcol];
#pragma unroll
        for (int mi = 0; mi < 4; ++mi)
#pragma unroll
            for (int rg = 0; rg < 4; ++rg) {
                int tok = 16 * mi + 4 * g + rg;
                size_t r = (size_t)(rbase + (tok >> 3) * 256 + (tok & 7));
                out[r * 256 + gcol] = acc2[mi][nj][rg] + bo;
            }
    }
}

// ---------------------------------------------------------------------------
extern "C" void kernel_launch(void* const* d_in, const int* in_sizes, int n_in,
                              void* d_out, int out_size, void* d_ws, size_t ws_size,
                              hipStream_t stream) {
    const float* x       = (const float*)d_in[0];
    const float* w_qkv   = (const float*)d_in[1];
    const float* pos_emb = (const float*)d_in[2];
    const float* w_out   = (const float*)d_in[3];
    const float* b_out   = (const float*)d_in[4];
    const int*   rel_idx = (const int*)d_in[5];

    char* ws = (char*)d_ws;
    bf16_t* wpk   = (bf16_t*)(ws + WPK_OFF);
    bf16_t* woutT = (bf16_t*)(ws + WOUTT_OFF);
    float*  biasP = (float*)(ws + BIASP_OFF);
    float*  out   = (float*)d_out;

    prep_kernel<<<1040, 256, 0, stream>>>(w_qkv, w_out, pos_emb, rel_idx,
                                          wpk, woutT, biasP);
    fused_kernel<<<2048, 512, 0, stream>>>(x, wpk, biasP, woutT, b_out, out);
}